// Round 9
// baseline (159.372 us; speedup 1.0000x reference)
//
#include <hip/hip_runtime.h>
#include <hip/hip_bf16.h>

// QuIP#-style quantized linear. R9: probe the qgemm wall. Harness analysis
// (Dispatch_Id step 33/iter) shows ~30 restore/poison dispatches inside every
// timed iteration ~= the constant ~88us "rest" -> unoptimizable. qgemm is the
// only lever. This round: 32-waves/CU config (1024 blocks, block=128n x 512k,
// waves split k-halves, 32 zpart pieces; ws-branched, fallback = R6-exact) +
// nt on the STREAMING qidxs index loads (codebook L2 protection).

typedef __attribute__((ext_vector_type(16))) float f32x16;
typedef __attribute__((ext_vector_type(8))) __bf16 bf16x8;
typedef __attribute__((ext_vector_type(4))) __bf16 bf16x4;
typedef __attribute__((ext_vector_type(4))) int i32x4;

#define IN_F 8192
#define OUT_F 8192
#define TOKENS 32
#define KCHUNK 512
#define CH (KCHUNK / 8)            // 64 16B-chunks per token row in LDS
#define DG 5                       // gather lookahead (groups)
#define DI 7                       // idx lookahead (groups)
#define INV_SQRT_8192 0.011048543456039806f
#define PAD(i) ((i) + ((i) >> 5))

// ---------------- register FWHT-32 ----------------
__device__ inline void fwht32_reg(float* r) {
    #pragma unroll
    for (int h = 1; h < 32; h <<= 1)
        #pragma unroll
        for (int i = 0; i < 32; i += 2 * h)
            #pragma unroll
            for (int j = 0; j < h; ++j) {
                float a = r[i + j], b = r[i + j + h];
                r[i + j] = a + b;
                r[i + j + h] = a - b;
            }
}

// ---------------- full FWHT-8192 in padded LDS, 256 threads ----------------
__device__ inline void fwht8192_lds(float* s, int tid) {
    float r[32];
    int b1 = tid * 32;                       // pass 1: bits 0-4
    #pragma unroll
    for (int j = 0; j < 32; ++j) r[j] = s[PAD(b1 + j)];
    fwht32_reg(r);
    #pragma unroll
    for (int j = 0; j < 32; ++j) s[PAD(b1 + j)] = r[j];
    __syncthreads();
    int b2 = (tid & 31) + (tid >> 5) * 1024; // pass 2: bits 5-9
    #pragma unroll
    for (int j = 0; j < 32; ++j) r[j] = s[PAD(b2 + 32 * j)];
    fwht32_reg(r);
    #pragma unroll
    for (int j = 0; j < 32; ++j) s[PAD(b2 + 32 * j)] = r[j];
    __syncthreads();
    #pragma unroll
    for (int jj = 0; jj < 4; ++jj) {         // pass 3: bits 10-12
        float g[8];
        int b3 = tid * 4 + jj;
        #pragma unroll
        for (int k = 0; k < 8; ++k) g[k] = s[PAD(b3 + 1024 * k)];
        #pragma unroll
        for (int h = 1; h < 8; h <<= 1)
            #pragma unroll
            for (int i = 0; i < 8; i += 2 * h)
                #pragma unroll
                for (int j = 0; j < h; ++j) {
                    float a = g[i + j], b = g[i + j + h];
                    g[i + j] = a + b;
                    g[i + j + h] = a - b;
                }
        #pragma unroll
        for (int k = 0; k < 8; ++k) s[PAD(b3 + 1024 * k)] = g[k];
    }
    __syncthreads();
}

// ---------------- kernel 1: codebook cvt + input FWHT ----------------
__global__ __launch_bounds__(256)
void prep_kernel(const float* __restrict__ cb, __bf16* __restrict__ cbb,
                 const float* __restrict__ x, const float* __restrict__ su,
                 __bf16* __restrict__ xh) {
    __shared__ float s[8192 + 256];
    const int tid = threadIdx.x;
    if (blockIdx.x < 512) {
        int i = blockIdx.x * 256 + tid;
        float4 v = ((const float4*)cb)[i];
        bf16x4 o;
        o[0] = (__bf16)v.x; o[1] = (__bf16)v.y;
        o[2] = (__bf16)v.z; o[3] = (__bf16)v.w;
        ((bf16x4*)cbb)[i] = o;
        return;
    }
    const int t = blockIdx.x - 512;
    #pragma unroll
    for (int i = tid; i < IN_F; i += 256)
        s[PAD(i)] = x[t * IN_F + i] * su[i];
    __syncthreads();
    fwht8192_lds(s, tid);
    #pragma unroll
    for (int i = tid; i < IN_F; i += 256)
        xh[t * IN_F + i] = (__bf16)(s[PAD(i)] * INV_SQRT_8192);
}

// ---- kernel 2a: R6-exact fallback (16 pieces, 512 blocks, 16 waves/CU) ----
__global__ __launch_bounds__(512, 4)
void qgemm16_kernel(const int* __restrict__ qidxs,
                    const __bf16* __restrict__ cb,
                    const __bf16* __restrict__ xh,
                    __bf16* __restrict__ zpart) {
    __shared__ __align__(16) __bf16 xt[TOKENS * KCHUNK];   // 32 KB
    const int ks = blockIdx.x & 15;
    const int nb = blockIdx.x >> 4;
    const int tid = threadIdx.x;
    const int wave = tid >> 6, lane = tid & 63;
    const int h = lane >> 5, lc = lane & 31;
    const int n = nb * 256 + wave * 32 + lc;

    #pragma unroll
    for (int i = 0; i < 4; ++i) {
        int f = i * 512 + tid, r = f >> 6, c = f & 63;
        i32x4 v = *(const i32x4*)(xh + (size_t)r * IN_F + ks * KCHUNK + c * 8);
        *(i32x4*)(xt + ((r * CH + (c ^ (r & 7))) << 3)) = v;
    }
    __syncthreads();    // the only barrier

    const int* qrow = qidxs + (size_t)n * (IN_F / 8) + ks * CH;
    const bf16x8* cbv = (const bf16x8*)cb;

    f32x16 acc;
    #pragma unroll
    for (int i = 0; i < 16; ++i) acc[i] = 0.f;

    i32x4 iv[16];
    bf16x8 bfr[16][2];

    #pragma unroll
    for (int g = 0; g < DI; ++g)
        iv[g] = __builtin_nontemporal_load((const i32x4*)(qrow + g * 4));
    #pragma unroll
    for (int g = 0; g < DG; ++g) {
        bfr[g][0] = cbv[h ? iv[g][1] : iv[g][0]];
        bfr[g][1] = cbv[h ? iv[g][3] : iv[g][2]];
    }

    #pragma unroll
    for (int g = 0; g < 16; ++g) {
        if (g + DI < 16)
            iv[g + DI] = __builtin_nontemporal_load(
                (const i32x4*)(qrow + (g + DI) * 4));
        if (g + DG < 16) {
            bfr[g + DG][0] = cbv[h ? iv[g + DG][1] : iv[g + DG][0]];
            bfr[g + DG][1] = cbv[h ? iv[g + DG][3] : iv[g + DG][2]];
        }
        #pragma unroll
        for (int sgi = 0; sgi < 2; ++sgi) {
            const int T = 2 * g + sgi;
            bf16x8 a = *(const bf16x8*)(xt +
                          ((lc * CH + ((2 * T + h) ^ (lc & 7))) << 3));
            acc = __builtin_amdgcn_mfma_f32_32x32x16_bf16(a, bfr[g][sgi],
                                                          acc, 0, 0, 0);
        }
    }

    __bf16* zp = zpart + ((size_t)ks * TOKENS) * OUT_F + n;
    #pragma unroll
    for (int r = 0; r < 16; ++r) {
        int m = (r & 3) + 4 * h + 8 * (r >> 2);
        zp[(size_t)m * OUT_F] = (__bf16)acc[r];
    }
}

// ---- kernel 2b: 32-piece / 32-waves-per-CU probe ----
// 1024 blocks (64 nb x 16 ks) x 512 thr. Block = 128 n x 512 k; wave(ng,kh)
// = 32 n x 256 k (NG=8 groups). LDS 32 KB -> 4 blocks/CU; (512,8) caps VGPR
// at 64 -> 32 waves/CU resident.
__global__ __launch_bounds__(512, 8)
void qgemm32_kernel(const int* __restrict__ qidxs,
                    const __bf16* __restrict__ cb,
                    const __bf16* __restrict__ xh,
                    __bf16* __restrict__ zpart) {
    __shared__ __align__(16) __bf16 xt[TOKENS * KCHUNK];   // 32 KB
    const int ks = blockIdx.x & 15;
    const int nb = blockIdx.x >> 4;                        // 0..63
    const int tid = threadIdx.x;
    const int wave = tid >> 6, lane = tid & 63;
    const int ng = wave & 3, kh = wave >> 2;               // n-group, k-half
    const int h = lane >> 5, lc = lane & 31;
    const int n = nb * 128 + ng * 32 + lc;

    #pragma unroll
    for (int i = 0; i < 4; ++i) {
        int f = i * 512 + tid, r = f >> 6, c = f & 63;
        i32x4 v = *(const i32x4*)(xh + (size_t)r * IN_F + ks * KCHUNK + c * 8);
        *(i32x4*)(xt + ((r * CH + (c ^ (r & 7))) << 3)) = v;
    }
    __syncthreads();    // the only barrier

    const int* qrow = qidxs + (size_t)n * (IN_F / 8) + ks * CH + kh * 32;
    const bf16x8* cbv = (const bf16x8*)cb;

    f32x16 acc;
    #pragma unroll
    for (int i = 0; i < 16; ++i) acc[i] = 0.f;

    i32x4 iv[8];
    bf16x8 bfr[8][2];

    #pragma unroll
    for (int g = 0; g < DI; ++g)
        iv[g] = __builtin_nontemporal_load((const i32x4*)(qrow + g * 4));
    #pragma unroll
    for (int g = 0; g < DG; ++g) {
        bfr[g][0] = cbv[h ? iv[g][1] : iv[g][0]];
        bfr[g][1] = cbv[h ? iv[g][3] : iv[g][2]];
    }

    #pragma unroll
    for (int g = 0; g < 8; ++g) {
        if (g + DI < 8)
            iv[g + DI] = __builtin_nontemporal_load(
                (const i32x4*)(qrow + (g + DI) * 4));
        if (g + DG < 8) {
            bfr[g + DG][0] = cbv[h ? iv[g + DG][1] : iv[g + DG][0]];
            bfr[g + DG][1] = cbv[h ? iv[g + DG][3] : iv[g + DG][2]];
        }
        #pragma unroll
        for (int sgi = 0; sgi < 2; ++sgi) {
            const int T = kh * 16 + 2 * g + sgi;           // tile in 512k
            bf16x8 a = *(const bf16x8*)(xt +
                          ((lc * CH + ((2 * T + h) ^ (lc & 7))) << 3));
            acc = __builtin_amdgcn_mfma_f32_32x32x16_bf16(a, bfr[g][sgi],
                                                          acc, 0, 0, 0);
        }
    }

    const int p = ks * 2 + kh;                             // piece 0..31
    __bf16* zp = zpart + ((size_t)p * TOKENS) * OUT_F + n;
    #pragma unroll
    for (int r = 0; r < 16; ++r) {
        int m = (r & 3) + 4 * h + 8 * (r >> 2);
        zp[(size_t)m * OUT_F] = (__bf16)acc[r];
    }
}

// ------- kernel 3: out = fwht(sum_p zpart)/sqrt(n) * SV * Wscale ----------
template <int PIECES>
__global__ __launch_bounds__(256)
void zsum_kernel(const __bf16* __restrict__ zpart, const float* __restrict__ sv,
                 const float* __restrict__ wscale, float* __restrict__ out) {
    __shared__ float s[8192 + 256];
    const int t = blockIdx.x, tid = threadIdx.x;
    #pragma unroll
    for (int cc = 0; cc < 4; ++cc) {
        int col = cc * 2048 + tid * 8;
        float a[8] = {0.f, 0.f, 0.f, 0.f, 0.f, 0.f, 0.f, 0.f};
        #pragma unroll
        for (int p = 0; p < PIECES; ++p) {
            bf16x8 v = *(const bf16x8*)(zpart +
                         ((size_t)(p * TOKENS + t)) * OUT_F + col);
            #pragma unroll
            for (int j = 0; j < 8; ++j) a[j] += (float)v[j];
        }
        #pragma unroll
        for (int j = 0; j < 8; ++j) s[PAD(col + j)] = a[j];
    }
    __syncthreads();
    fwht8192_lds(s, tid);
    const float sc = INV_SQRT_8192 * wscale[0];
    #pragma unroll
    for (int i = tid; i < OUT_F; i += 256)
        out[t * OUT_F + i] = s[PAD(i)] * sc * sv[i];
}

extern "C" void kernel_launch(void* const* d_in, const int* in_sizes, int n_in,
                              void* d_out, int out_size, void* d_ws, size_t ws_size,
                              hipStream_t stream) {
    const float* x      = (const float*)d_in[0];   // (32, 8192)
    const float* cb     = (const float*)d_in[1];   // (65536, 8)
    const int*   qidxs  = (const int*)d_in[2];     // (8192, 1024)
    const float* su     = (const float*)d_in[3];   // (8192,)
    const float* sv     = (const float*)d_in[4];   // (8192,)
    const float* wscale = (const float*)d_in[5];   // scalar
    float* out = (float*)d_out;                    // (32, 8192) fp32

    char* ws = (char*)d_ws;
    __bf16* cb_bf16 = (__bf16*)ws;                               // 1 MB
    __bf16* xh      = (__bf16*)(ws + (1u << 20));                // 512 KB
    __bf16* zpart   = (__bf16*)(ws + (1u << 20) + (512u << 10)); // 8/16 MB

    hipLaunchKernelGGL(prep_kernel, dim3(544), dim3(256), 0, stream,
                       cb, cb_bf16, x, su, xh);

    const size_t need32 = (1u << 20) + (512u << 10) +
                          (size_t)32 * TOKENS * OUT_F * 2;       // ~17.5 MB
    if (ws_size >= need32) {
        hipLaunchKernelGGL(qgemm32_kernel, dim3(1024), dim3(512), 0, stream,
                           qidxs, cb_bf16, xh, zpart);
        hipLaunchKernelGGL((zsum_kernel<32>), dim3(TOKENS), dim3(256), 0,
                           stream, zpart, sv, wscale, out);
    } else {
        hipLaunchKernelGGL(qgemm16_kernel, dim3(512), dim3(512), 0, stream,
                           qidxs, cb_bf16, xh, zpart);
        hipLaunchKernelGGL((zsum_kernel<16>), dim3(TOKENS), dim3(256), 0,
                           stream, zpart, sv, wscale, out);
    }
}

// Round 10
// 134.871 us; speedup vs baseline: 1.1817x; 1.1817x over previous
//
#include <hip/hip_runtime.h>
#include <hip/hip_bf16.h>

// QuIP#-style quantized linear. R10: R6-exact structure (48us champion) with
// the codebook gathers routed AROUND L1 via buffer_load sc0 (agent-coherent
// -> L1 bypass, L2 cached). Theory: per-CU L1 miss-tracking (~64 lines) is
// the wall (occupancy 21->47% and pipeline depth 2->8 all left gather rate
// unchanged); 32768 line-misses/CU x ~225cyc / 64 outstanding ~= 48us = R6.
// sc0 requests use the L2-direct path. Fallback (no builtin): plain loads.

typedef __attribute__((ext_vector_type(16))) float f32x16;
typedef __attribute__((ext_vector_type(8))) __bf16 bf16x8;
typedef __attribute__((ext_vector_type(4))) __bf16 bf16x4;
typedef __attribute__((ext_vector_type(4))) int i32x4;

#define IN_F 8192
#define OUT_F 8192
#define TOKENS 32
#define KSPLIT 16
#define KCHUNK 512
#define CH (KCHUNK / 8)            // 64 16B-chunks per token row in LDS
#define DG 5                       // gather lookahead (groups)
#define DI 7                       // idx lookahead (groups)
#define INV_SQRT_8192 0.011048543456039806f
#define PAD(i) ((i) + ((i) >> 5))

#if __has_builtin(__builtin_amdgcn_raw_buffer_load_b128) && \
    __has_builtin(__builtin_amdgcn_make_buffer_rsrc)
#define HAVE_BUF 1
#else
#define HAVE_BUF 0
#endif

// ---------------- register FWHT-32 ----------------
__device__ inline void fwht32_reg(float* r) {
    #pragma unroll
    for (int h = 1; h < 32; h <<= 1)
        #pragma unroll
        for (int i = 0; i < 32; i += 2 * h)
            #pragma unroll
            for (int j = 0; j < h; ++j) {
                float a = r[i + j], b = r[i + j + h];
                r[i + j] = a + b;
                r[i + j + h] = a - b;
            }
}

// ---------------- full FWHT-8192 in padded LDS, 256 threads ----------------
__device__ inline void fwht8192_lds(float* s, int tid) {
    float r[32];
    int b1 = tid * 32;                       // pass 1: bits 0-4
    #pragma unroll
    for (int j = 0; j < 32; ++j) r[j] = s[PAD(b1 + j)];
    fwht32_reg(r);
    #pragma unroll
    for (int j = 0; j < 32; ++j) s[PAD(b1 + j)] = r[j];
    __syncthreads();
    int b2 = (tid & 31) + (tid >> 5) * 1024; // pass 2: bits 5-9
    #pragma unroll
    for (int j = 0; j < 32; ++j) r[j] = s[PAD(b2 + 32 * j)];
    fwht32_reg(r);
    #pragma unroll
    for (int j = 0; j < 32; ++j) s[PAD(b2 + 32 * j)] = r[j];
    __syncthreads();
    #pragma unroll
    for (int jj = 0; jj < 4; ++jj) {         // pass 3: bits 10-12
        float g[8];
        int b3 = tid * 4 + jj;
        #pragma unroll
        for (int k = 0; k < 8; ++k) g[k] = s[PAD(b3 + 1024 * k)];
        #pragma unroll
        for (int h = 1; h < 8; h <<= 1)
            #pragma unroll
            for (int i = 0; i < 8; i += 2 * h)
                #pragma unroll
                for (int j = 0; j < h; ++j) {
                    float a = g[i + j], b = g[i + j + h];
                    g[i + j] = a + b;
                    g[i + j + h] = a - b;
                }
        #pragma unroll
        for (int k = 0; k < 8; ++k) s[PAD(b3 + 1024 * k)] = g[k];
    }
    __syncthreads();
}

// ---------------- kernel 1: codebook cvt + input FWHT ----------------
__global__ __launch_bounds__(256)
void prep_kernel(const float* __restrict__ cb, __bf16* __restrict__ cbb,
                 const float* __restrict__ x, const float* __restrict__ su,
                 __bf16* __restrict__ xh) {
    __shared__ float s[8192 + 256];
    const int tid = threadIdx.x;
    if (blockIdx.x < 512) {
        int i = blockIdx.x * 256 + tid;
        float4 v = ((const float4*)cb)[i];
        bf16x4 o;
        o[0] = (__bf16)v.x; o[1] = (__bf16)v.y;
        o[2] = (__bf16)v.z; o[3] = (__bf16)v.w;
        ((bf16x4*)cbb)[i] = o;
        return;
    }
    const int t = blockIdx.x - 512;
    #pragma unroll
    for (int i = tid; i < IN_F; i += 256)
        s[PAD(i)] = x[t * IN_F + i] * su[i];
    __syncthreads();
    fwht8192_lds(s, tid);
    #pragma unroll
    for (int i = tid; i < IN_F; i += 256)
        xh[t * IN_F + i] = (__bf16)(s[PAD(i)] * INV_SQRT_8192);
}

// ---------------- kernel 2: zpart = xh @ W^T (R6 + sc0 gathers) -----------
__global__ __launch_bounds__(512, 4)
void qgemm_kernel(const int* __restrict__ qidxs,
                  const __bf16* __restrict__ cb,
                  const __bf16* __restrict__ xh,
                  __bf16* __restrict__ zpart) {
    __shared__ __align__(16) __bf16 xt[TOKENS * KCHUNK];   // 32 KB
    const int ks = blockIdx.x & 15;
    const int nb = blockIdx.x >> 4;
    const int tid = threadIdx.x;
    const int wave = tid >> 6, lane = tid & 63;
    const int h = lane >> 5, lc = lane & 31;
    const int n = nb * 256 + wave * 32 + lc;

    // stage xh k-slice (32 tok x 512 k) -> LDS, 16B chunks xor-swizzled
    #pragma unroll
    for (int i = 0; i < 4; ++i) {
        int f = i * 512 + tid, r = f >> 6, c = f & 63;
        i32x4 v = *(const i32x4*)(xh + (size_t)r * IN_F + ks * KCHUNK + c * 8);
        *(i32x4*)(xt + ((r * CH + (c ^ (r & 7))) << 3)) = v;
    }
    __syncthreads();    // the only barrier

    const int* qrow = qidxs + (size_t)n * (IN_F / 8) + ks * CH;

#if HAVE_BUF
    // SRD over the bf16 codebook (1 MB). aux=1 -> SC0: L1-bypass, L2-cached.
    __amdgpu_buffer_rsrc_t rsrc = __builtin_amdgcn_make_buffer_rsrc(
        (void*)cb, (short)0, 65536 * 16, 0x00020000);
    #define GATHER(ix) __builtin_bit_cast(bf16x8, \
        __builtin_amdgcn_raw_buffer_load_b128(rsrc, (ix) << 4, 0, 1))
#else
    const bf16x8* cbv = (const bf16x8*)cb;
    #define GATHER(ix) (cbv[ix])
#endif

    f32x16 acc;
    #pragma unroll
    for (int i = 0; i < 16; ++i) acc[i] = 0.f;

    i32x4 iv[16];
    bf16x8 bfr[16][2];

    #pragma unroll
    for (int g = 0; g < DI; ++g)
        iv[g] = *(const i32x4*)(qrow + g * 4);
    #pragma unroll
    for (int g = 0; g < DG; ++g) {
        bfr[g][0] = GATHER(h ? iv[g][1] : iv[g][0]);
        bfr[g][1] = GATHER(h ? iv[g][3] : iv[g][2]);
    }

    #pragma unroll
    for (int g = 0; g < 16; ++g) {
        if (g + DI < 16)
            iv[g + DI] = *(const i32x4*)(qrow + (g + DI) * 4);
        if (g + DG < 16) {
            bfr[g + DG][0] = GATHER(h ? iv[g + DG][1] : iv[g + DG][0]);
            bfr[g + DG][1] = GATHER(h ? iv[g + DG][3] : iv[g + DG][2]);
        }
        #pragma unroll
        for (int sgi = 0; sgi < 2; ++sgi) {
            const int T = 2 * g + sgi;
            bf16x8 a = *(const bf16x8*)(xt +
                          ((lc * CH + ((2 * T + h) ^ (lc & 7))) << 3));
            acc = __builtin_amdgcn_mfma_f32_32x32x16_bf16(a, bfr[g][sgi],
                                                          acc, 0, 0, 0);
        }
    }

    // D[m=(r&3)+4h+8(r>>2)][n=lc] -> bf16 partials
    __bf16* zp = zpart + ((size_t)ks * TOKENS) * OUT_F + n;
    #pragma unroll
    for (int r = 0; r < 16; ++r) {
        int m = (r & 3) + 4 * h + 8 * (r >> 2);
        zp[(size_t)m * OUT_F] = (__bf16)acc[r];
    }
}

// ------- kernel 3: out = fwht(sum_ks zpart)/sqrt(n) * SV * Wscale ----------
__global__ __launch_bounds__(256)
void zsum_kernel(const __bf16* __restrict__ zpart, const float* __restrict__ sv,
                 const float* __restrict__ wscale, float* __restrict__ out) {
    __shared__ float s[8192 + 256];
    const int t = blockIdx.x, tid = threadIdx.x;
    #pragma unroll
    for (int cc = 0; cc < 4; ++cc) {
        int col = cc * 2048 + tid * 8;
        float a[8] = {0.f, 0.f, 0.f, 0.f, 0.f, 0.f, 0.f, 0.f};
        #pragma unroll
        for (int ks = 0; ks < KSPLIT; ++ks) {
            bf16x8 v = *(const bf16x8*)(zpart +
                         ((size_t)(ks * TOKENS + t)) * OUT_F + col);
            #pragma unroll
            for (int j = 0; j < 8; ++j) a[j] += (float)v[j];
        }
        #pragma unroll
        for (int j = 0; j < 8; ++j) s[PAD(col + j)] = a[j];
    }
    __syncthreads();
    fwht8192_lds(s, tid);
    const float sc = INV_SQRT_8192 * wscale[0];
    #pragma unroll
    for (int i = tid; i < OUT_F; i += 256)
        out[t * OUT_F + i] = s[PAD(i)] * sc * sv[i];
}

extern "C" void kernel_launch(void* const* d_in, const int* in_sizes, int n_in,
                              void* d_out, int out_size, void* d_ws, size_t ws_size,
                              hipStream_t stream) {
    const float* x      = (const float*)d_in[0];   // (32, 8192)
    const float* cb     = (const float*)d_in[1];   // (65536, 8)
    const int*   qidxs  = (const int*)d_in[2];     // (8192, 1024)
    const float* su     = (const float*)d_in[3];   // (8192,)
    const float* sv     = (const float*)d_in[4];   // (8192,)
    const float* wscale = (const float*)d_in[5];   // scalar
    float* out = (float*)d_out;                    // (32, 8192) fp32

    char* ws = (char*)d_ws;
    __bf16* cb_bf16 = (__bf16*)ws;                               // 1 MB
    __bf16* xh      = (__bf16*)(ws + (1u << 20));                // 512 KB
    __bf16* zpart   = (__bf16*)(ws + (1u << 20) + (512u << 10)); // 8 MB bf16

    hipLaunchKernelGGL(prep_kernel, dim3(544), dim3(256), 0, stream,
                       cb, cb_bf16, x, su, xh);
    hipLaunchKernelGGL(qgemm_kernel, dim3(32 * KSPLIT), dim3(512), 0, stream,
                       qidxs, cb_bf16, xh, zpart);
    hipLaunchKernelGGL(zsum_kernel, dim3(TOKENS), dim3(256), 0, stream,
                       zpart, sv, wscale, out);
}